// Round 15
// baseline (136.179 us; speedup 1.0000x reference)
//
#include <hip/hip_runtime.h>

#define DIM 1024
#define HID 512
#define NE 8
#define T_TOK 4096
#define BMPAD 128
#define PAD_ROUTED (T_TOK*2 + NE*BMPAD)     // 9216
#define SHARED_BASE PAD_ROUTED              // 9216
#define TOTAL_SLOTS (SHARED_BASE + T_TOK)   // 13312
#define NRT 104                             // max row-tiles: <=72 routed + 32 shared

// meta layout: [26] routed_end, [32..] rt table (e,base)*NRT
#define M_REND 26
#define M_RT 32

// k_front block split
#define FRONT_GATE 256
#define FRONT_CONV 2048

typedef __attribute__((ext_vector_type(4))) float f32x4;
typedef __attribute__((ext_vector_type(8))) short s16x8;

__device__ __forceinline__ unsigned short f2bf(float f) {
    union { float f; unsigned int u; } v; v.f = f;
    unsigned int u = v.u;
    u += 0x7fffu + ((u >> 16) & 1u);   // RNE
    return (unsigned short)(u >> 16);
}
__device__ __forceinline__ float bf2f(unsigned short s) {
    union { unsigned int u; float f; } v; v.u = ((unsigned int)s) << 16;
    return v.f;
}

// async global(16B/lane) -> LDS (wave-uniform base + lane*16); global src may be per-lane
__device__ __forceinline__ void gload_lds16(const void* g, void* lds) {
    __builtin_amdgcn_global_load_lds(
        (const __attribute__((address_space(1))) unsigned int*)g,
        (__attribute__((address_space(3))) unsigned int*)lds, 16, 0, 0);
}

__device__ __forceinline__ unsigned long long pack4(f32x4 v) {
    unsigned long long o = 0;
    o |= (unsigned long long)f2bf(v[0]);
    o |= (unsigned long long)f2bf(v[1]) << 16;
    o |= (unsigned long long)f2bf(v[2]) << 32;
    o |= (unsigned long long)f2bf(v[3]) << 48;
    return o;
}

// ---------------- front: gate (blocks 0..255) || conv weights+x (rest) ----------------
// W13 layout: per expert, 1024 rows; 32-row groups: rows 0..15 = w1 h-group, 16..31 = w3.
__global__ __launch_bounds__(256) void k_front(const float* __restrict__ x,
                                               const float* __restrict__ gw,
                                               const float* __restrict__ w1,
                                               const float* __restrict__ sw1,
                                               const float* __restrict__ w3,
                                               const float* __restrict__ sw3,
                                               const float* __restrict__ w2,
                                               const float* __restrict__ sw2,
                                               unsigned short* __restrict__ w13,
                                               unsigned short* __restrict__ w2b,
                                               unsigned short* __restrict__ xb,
                                               int* __restrict__ top_e,
                                               float* __restrict__ top_s) {
    int bid = blockIdx.x, tid = threadIdx.x;
    if (bid >= FRONT_GATE) {
        const long HD = (long)HID * DIM;
        const long E0 = (long)NE * HD;
        const long S0 = E0;
        const long S1 = S0 + HD;
        const long S2 = S1 + E0;
        const long S3 = S2 + HD;
        const long S4 = S3 + E0;
        const long S5 = S4 + HD;
        const long TOT = S5 + (long)T_TOK * DIM;
        long stride = (long)FRONT_CONV * 256 * 4;
        for (long i = ((long)(bid - FRONT_GATE) * 256 + tid) * 4; i < TOT; i += stride) {
            const float* src; unsigned short* dst; long off;
            if (i < S0) {
                off = i;
                long e = off / HD, r = off % HD, h = r / DIM, k = r % DIM;
                src = w1;
                dst = w13 + e * (1024L * DIM) + (((h >> 4) * 32 + (h & 15)) * DIM + k);
            } else if (i < S1) {
                off = i - S0;
                long h = off / DIM, k = off % DIM;
                src = sw1;
                dst = w13 + 8L * (1024L * DIM) + (((h >> 4) * 32 + (h & 15)) * DIM + k);
            } else if (i < S2) {
                off = i - S1;
                long e = off / HD, r = off % HD, h = r / DIM, k = r % DIM;
                src = w3;
                dst = w13 + e * (1024L * DIM) + (((h >> 4) * 32 + 16 + (h & 15)) * DIM + k);
            } else if (i < S3) {
                off = i - S2;
                long h = off / DIM, k = off % DIM;
                src = sw3;
                dst = w13 + 8L * (1024L * DIM) + (((h >> 4) * 32 + 16 + (h & 15)) * DIM + k);
            } else if (i < S4) {
                off = i - S3;
                src = w2; dst = w2b + off;
            } else if (i < S5) {
                off = i - S4;
                src = sw2; dst = w2b + (long)NE * DIM * HID + off;
            } else {
                off = i - S5;
                src = x; dst = xb + off;
            }
            *(unsigned long long*)dst = pack4(*(const f32x4*)&src[off]);
        }
        return;
    }
    // ---- gate: 16 tokens per block, gw in registers ----
    int wv = tid >> 6, lane = tid & 63;
    f32x4 gwr[4][NE];
#pragma unroll
    for (int j0 = 0; j0 < 4; j0++) {
        int j = j0 * 64 + lane;
#pragma unroll
        for (int e = 0; e < NE; e++)
            gwr[j0][e] = *(const f32x4*)&gw[e * DIM + j * 4];
    }
    int t0 = bid * 16 + wv * 4;
    for (int tt = 0; tt < 4; tt++) {
        int t = t0 + tt;
        float p[NE];
#pragma unroll
        for (int e = 0; e < NE; e++) p[e] = 0.f;
        const f32x4* xr = (const f32x4*)(x + (size_t)t * DIM);
#pragma unroll
        for (int j0 = 0; j0 < 4; j0++) {
            f32x4 xv = xr[j0 * 64 + lane];
#pragma unroll
            for (int e = 0; e < NE; e++) {
                f32x4 wv4 = gwr[j0][e];
                p[e] += xv[0] * wv4[0] + xv[1] * wv4[1] + xv[2] * wv4[2] + xv[3] * wv4[3];
            }
        }
#pragma unroll
        for (int e = 0; e < NE; e++) {
            float v = p[e];
            for (int off = 32; off; off >>= 1) v += __shfl_xor(v, off, 64);
            p[e] = v;
        }
        if (lane == 0) {
            float s[NE];
#pragma unroll
            for (int e = 0; e < NE; e++) s[e] = 1.f / (1.f + expf(-p[e]));
            int e0 = 0;
#pragma unroll
            for (int e = 1; e < NE; e++) if (s[e] > s[e0]) e0 = e;
            int e1 = (e0 == 0) ? 1 : 0;
#pragma unroll
            for (int e = 0; e < NE; e++) if (e != e0 && s[e] > s[e1]) e1 = e;
            top_e[t * 2 + 0] = e0;  top_e[t * 2 + 1] = e1;
            top_s[t * 2 + 0] = s[e0]; top_s[t * 2 + 1] = s[e1];
        }
    }
}

// ---------------- route: single-block counting sort, wave-parallel scan ----------------
__global__ __launch_bounds__(256) void k_route(const int* __restrict__ top_e,
                                               const float* __restrict__ top_s,
                                               int* __restrict__ meta,
                                               int* __restrict__ slot_of,
                                               int* __restrict__ row_tok,
                                               float* __restrict__ row_sc) {
    __shared__ int lcnt[256][9];
    __shared__ int cntS[NE], poffS[NE], padS[NE];
    int tid = threadIdx.x;
    int base = tid * 32;

    int c0=0,c1=0,c2=0,c3=0,c4=0,c5=0,c6=0,c7=0;
    for (int i = 0; i < 32; i++) {
        int e = top_e[base + i];
        c0 += (e==0); c1 += (e==1); c2 += (e==2); c3 += (e==3);
        c4 += (e==4); c5 += (e==5); c6 += (e==6); c7 += (e==7);
    }
    lcnt[tid][0]=c0; lcnt[tid][1]=c1; lcnt[tid][2]=c2; lcnt[tid][3]=c3;
    lcnt[tid][4]=c4; lcnt[tid][5]=c5; lcnt[tid][6]=c6; lcnt[tid][7]=c7;
    __syncthreads();
    {
        int e = tid >> 5, l = tid & 31;
        int tmp[8], s = 0;
#pragma unroll
        for (int k = 0; k < 8; k++) { tmp[k] = lcnt[l * 8 + k][e]; s += tmp[k]; }
        int inc = s;
#pragma unroll
        for (int off = 1; off < 32; off <<= 1) {
            int v = __shfl_up(inc, off, 32);
            if (l >= off) inc += v;
        }
        int run = inc - s;
        if (l == 31) cntS[e] = inc;
#pragma unroll
        for (int k = 0; k < 8; k++) { lcnt[l * 8 + k][e] = run; run += tmp[k]; }
    }
    __syncthreads();
    if (tid == 0) {
        int off = 0, rt = 0;
        for (int e = 0; e < NE; e++) {
            poffS[e] = off;
            int pad = ((cntS[e] + BMPAD - 1) / BMPAD) * BMPAD;
            padS[e] = pad;
            for (int b = 0; b * BMPAD < pad; b++) {
                meta[M_RT + rt * 2] = e;
                meta[M_RT + rt * 2 + 1] = off + b * BMPAD;
                rt++;
            }
            off += pad;
        }
        meta[M_REND] = off;
        for (int b = 0; b < T_TOK / BMPAD; b++) {
            meta[M_RT + rt * 2] = NE;
            meta[M_RT + rt * 2 + 1] = SHARED_BASE + b * BMPAD;
            rt++;
        }
        for (; rt < NRT; rt++) { meta[M_RT + rt * 2] = -1; meta[M_RT + rt * 2 + 1] = 0; }
    }
    __syncthreads();
    int p0 = poffS[0] + lcnt[tid][0], p1 = poffS[1] + lcnt[tid][1];
    int p2 = poffS[2] + lcnt[tid][2], p3 = poffS[3] + lcnt[tid][3];
    int p4 = poffS[4] + lcnt[tid][4], p5 = poffS[5] + lcnt[tid][5];
    int p6 = poffS[6] + lcnt[tid][6], p7 = poffS[7] + lcnt[tid][7];
    for (int i = 0; i < 32; i++) {
        int p = base + i;
        int e = top_e[p];
        int slot = 0;
        slot = (e==0) ? p0 : slot;  p0 += (e==0);
        slot = (e==1) ? p1 : slot;  p1 += (e==1);
        slot = (e==2) ? p2 : slot;  p2 += (e==2);
        slot = (e==3) ? p3 : slot;  p3 += (e==3);
        slot = (e==4) ? p4 : slot;  p4 += (e==4);
        slot = (e==5) ? p5 : slot;  p5 += (e==5);
        slot = (e==6) ? p6 : slot;  p6 += (e==6);
        slot = (e==7) ? p7 : slot;  p7 += (e==7);
        slot_of[p] = slot;
        row_tok[slot] = p >> 1;
        row_sc[slot] = top_s[p];
    }
    __syncthreads();
    for (int e = 0; e < NE; e++) {
        int s0 = poffS[e] + cntS[e], s1 = poffS[e] + padS[e];
        for (int i = s0 + tid; i < s1; i += 256) { row_tok[i] = 0; row_sc[i] = 0.f; }
    }
}

// ---------------- GEMM1: m97 structure. 128x128(combined) tile, BK=64, 256 thr, 1-buf 32KB ----------------
// wave (wr, wc in 2x2) owns 64 rows x 64 combined cols; W13 B-matrix; in-lane SwiGLU pairing.
__global__ __launch_bounds__(256) void k_gemm1(const unsigned short* __restrict__ xb,
                                               const unsigned short* __restrict__ w13,
                                               const int* __restrict__ meta,
                                               const int* __restrict__ row_tok,
                                               const float* __restrict__ row_sc,
                                               unsigned short* __restrict__ g) {
    int flat = blockIdx.y * NRT + blockIdx.x;
    int work = (flat & 7) * NRT + (flat >> 3);       // bijective XCD chunking (832 = 8*104)
    int rt = work >> 3, ct = work & 7;
    int e = meta[M_RT + rt * 2];
    if (e < 0) return;
    int rowbase = meta[M_RT + rt * 2 + 1];
    bool shared_tile = (e == NE);

    __shared__ __align__(16) unsigned short As[128 * 64];   // 16KB
    __shared__ __align__(16) unsigned short Bs[128 * 64];   // 16KB

    int tid = threadIdx.x, w = tid >> 6, lane = tid & 63;
    int l15 = lane & 15, kq = lane >> 4;
    int wr = w >> 1, wc = w & 1;
    int lr = lane >> 3;
    int lcs = ((lane & 7) ^ lr) << 4;   // XOR-swizzled source byte col (write side)
    int rx = l15 & 7;                   // read-side XOR key

    // per-lane A gather sources: 4 issues x 8 rows per wave (wave covers A rows w*32..+32)
    const char* asrc[4];
#pragma unroll
    for (int j = 0; j < 4; j++) {
        int slot = rowbase + w * 32 + j * 8 + lr;
        int tok = shared_tile ? (slot - SHARED_BASE) : row_tok[slot];
        asrc[j] = (const char*)xb + (size_t)tok * (DIM * 2) + lcs;
    }
    const char* Bb = (const char*)(w13 + (size_t)e * 1024 * DIM + (size_t)(ct * 128) * DIM);

    f32x4 acc[4][4];
#pragma unroll
    for (int m = 0; m < 4; m++)
#pragma unroll
        for (int n = 0; n < 4; n++) acc[m][n] = (f32x4){0.f, 0.f, 0.f, 0.f};

#pragma unroll 1
    for (int t = 0; t < 16; t++) {
        __syncthreads();                 // previous compute done before overwrite
#pragma unroll
        for (int j = 0; j < 4; j++) {
            int r0 = w * 32 + j * 8;
            gload_lds16(asrc[j] + t * 128, (char*)As + r0 * 128);
            gload_lds16(Bb + (size_t)(r0 + lr) * (DIM * 2) + t * 128 + lcs,
                        (char*)Bs + r0 * 128);
        }
        __syncthreads();                 // compiler drains vmcnt(0): staged data visible
#pragma unroll
        for (int kk = 0; kk < 64; kk += 32) {
            int sl = kq + (kk >> 3);
            s16x8 af[4], bf[4];
#pragma unroll
            for (int m = 0; m < 4; m++)
                af[m] = *(const s16x8*)&As[(wr * 64 + m * 16 + l15) * 64 + ((sl ^ rx) << 3)];
#pragma unroll
            for (int n = 0; n < 4; n++)
                bf[n] = *(const s16x8*)&Bs[(wc * 64 + n * 16 + l15) * 64 + ((sl ^ rx) << 3)];
#pragma unroll
            for (int m = 0; m < 4; m++)
#pragma unroll
                for (int n = 0; n < 4; n++)
                    acc[m][n] = __builtin_amdgcn_mfma_f32_16x16x32_bf16(af[m], bf[n], acc[m][n], 0, 0, 0);
        }
    }
    // epilogue: even/odd n-pairs are (w1,w3) cols of the same 16 hid cols
#pragma unroll
    for (int m = 0; m < 4; m++)
#pragma unroll
        for (int i = 0; i < 4; i++) {
            int row = rowbase + wr * 64 + m * 16 + kq * 4 + i;
            float sc = shared_tile ? 1.f : row_sc[row];
#pragma unroll
            for (int p = 0; p < 2; p++) {
                float h1 = sc * acc[m][2 * p][i];
                float h3 = sc * acc[m][2 * p + 1][i];
                float gv = h1 / (1.f + expf(-h1)) * h3;
                int hid = (ct * 4 + wc * 2 + p) * 16 + l15;
                g[(size_t)row * HID + hid] = f2bf(gv);
            }
        }
}

// ---------------- GEMM2: m97 structure. 128x128 tile, BK=64, 256 thr, 1-buf 32KB ----------------
__global__ __launch_bounds__(256) void k_gemm2(const unsigned short* __restrict__ g,
                                               const unsigned short* __restrict__ w2b,
                                               const int* __restrict__ meta,
                                               unsigned short* __restrict__ y) {
    int flat = blockIdx.y * NRT + blockIdx.x;
    int work = (flat & 7) * NRT + (flat >> 3);
    int rt = work >> 3, ct = work & 7;
    int e = meta[M_RT + rt * 2];
    if (e < 0) return;
    int rowbase = meta[M_RT + rt * 2 + 1];
    int nbase = ct * 128;

    __shared__ __align__(16) unsigned short As[128 * 64];
    __shared__ __align__(16) unsigned short Bs[128 * 64];

    int tid = threadIdx.x, w = tid >> 6, lane = tid & 63;
    int l15 = lane & 15, kq = lane >> 4;
    int wr = w >> 1, wc = w & 1;
    int lr = lane >> 3;
    int lcs = ((lane & 7) ^ lr) << 4;
    int rx = l15 & 7;

    const char* Ab = (const char*)(g + (size_t)rowbase * HID);
    const char* Bb = (const char*)(w2b + (size_t)e * DIM * HID + (size_t)nbase * HID);

    f32x4 acc[4][4];
#pragma unroll
    for (int m = 0; m < 4; m++)
#pragma unroll
        for (int n = 0; n < 4; n++) acc[m][n] = (f32x4){0.f, 0.f, 0.f, 0.f};

#pragma unroll 1
    for (int t = 0; t < 8; t++) {
        __syncthreads();
#pragma unroll
        for (int j = 0; j < 4; j++) {
            int r0 = w * 32 + j * 8;
            gload_lds16(Ab + (size_t)(r0 + lr) * (HID * 2) + t * 128 + lcs,
                        (char*)As + r0 * 128);
            gload_lds16(Bb + (size_t)(r0 + lr) * (HID * 2) + t * 128 + lcs,
                        (char*)Bs + r0 * 128);
        }
        __syncthreads();
#pragma unroll
        for (int kk = 0; kk < 64; kk += 32) {
            int sl = kq + (kk >> 3);
            s16x8 af[4], bf[4];
#pragma unroll
            for (int m = 0; m < 4; m++)
                af[m] = *(const s16x8*)&As[(wr * 64 + m * 16 + l15) * 64 + ((sl ^ rx) << 3)];
#pragma unroll
            for (int n = 0; n < 4; n++)
                bf[n] = *(const s16x8*)&Bs[(wc * 64 + n * 16 + l15) * 64 + ((sl ^ rx) << 3)];
#pragma unroll
            for (int m = 0; m < 4; m++)
#pragma unroll
                for (int n = 0; n < 4; n++)
                    acc[m][n] = __builtin_amdgcn_mfma_f32_16x16x32_bf16(af[m], bf[n], acc[m][n], 0, 0, 0);
        }
    }
#pragma unroll
    for (int m = 0; m < 4; m++)
#pragma unroll
        for (int n = 0; n < 4; n++)
#pragma unroll
            for (int i = 0; i < 4; i++) {
                int row = rowbase + wr * 64 + m * 16 + kq * 4 + i;
                int col = nbase + wc * 64 + n * 16 + l15;
                y[(size_t)row * DIM + col] = f2bf(acc[m][n][i]);
            }
}

// ---------------- combine: out[t] = y[s0]+y[s1]+y[shared+t] (fp32 out) ----------------
__global__ __launch_bounds__(256) void k_combine(const unsigned short* __restrict__ y,
                                                 const int* __restrict__ slot_of,
                                                 float* __restrict__ out) {
    int idx = blockIdx.x * 256 + threadIdx.x;
    int t = idx >> 7;
    int d = (idx & 127) << 3;
    int s0 = slot_of[2 * t], s1 = slot_of[2 * t + 1];
    s16x8 a = *(const s16x8*)&y[(size_t)s0 * DIM + d];
    s16x8 b = *(const s16x8*)&y[(size_t)s1 * DIM + d];
    s16x8 c = *(const s16x8*)&y[(size_t)(SHARED_BASE + t) * DIM + d];
    f32x4 o0, o1;
#pragma unroll
    for (int i = 0; i < 4; i++) {
        o0[i] = bf2f((unsigned short)a[i]) + bf2f((unsigned short)b[i]) + bf2f((unsigned short)c[i]);
        o1[i] = bf2f((unsigned short)a[i + 4]) + bf2f((unsigned short)b[i + 4]) + bf2f((unsigned short)c[i + 4]);
    }
    *(f32x4*)&out[(size_t)t * DIM + d + 0] = o0;
    *(f32x4*)&out[(size_t)t * DIM + d + 4] = o1;
}

extern "C" void kernel_launch(void* const* d_in, const int* in_sizes, int n_in,
                              void* d_out, int out_size, void* d_ws, size_t ws_size,
                              hipStream_t stream) {
    const float* x   = (const float*)d_in[0];
    const float* gw  = (const float*)d_in[1];
    const float* w1  = (const float*)d_in[2];
    const float* w2  = (const float*)d_in[3];
    const float* w3  = (const float*)d_in[4];
    const float* sw1 = (const float*)d_in[5];
    const float* sw2 = (const float*)d_in[6];
    const float* sw3 = (const float*)d_in[7];
    float* out = (float*)d_out;

    char* ws = (char*)d_ws;
    size_t off = 0;
    unsigned short* W13 = (unsigned short*)(ws + off); off += (size_t)9 * 1024 * DIM * 2;   // 18.9MB
    unsigned short* W2B = (unsigned short*)(ws + off); off += (size_t)9 * DIM * HID * 2;    // 9.4MB
    unsigned short* A1  = (unsigned short*)(ws + off); off += (size_t)TOTAL_SLOTS * DIM * 2; // Y aliases
    unsigned short* G   = (unsigned short*)(ws + off); off += (size_t)TOTAL_SLOTS * HID * 2;
    unsigned short* Y   = A1;                                // y written by gemm2
    unsigned short* XB  = A1 + (size_t)SHARED_BASE * DIM;    // bf16(x) = Y's shared region
    int*   TOPE = (int*)(ws + off);   off += T_TOK * 2 * 4;
    float* TOPS = (float*)(ws + off); off += T_TOK * 2 * 4;
    int*   SLOT = (int*)(ws + off);   off += T_TOK * 2 * 4;
    int*   RTOK = (int*)(ws + off);   off += TOTAL_SLOTS * 4;
    float* RSC  = (float*)(ws + off); off += TOTAL_SLOTS * 4;
    int*   META = (int*)(ws + off);   off += 1024;

    // fused front: gate || weights(W13 interleave, w2 linear)+x -> bf16
    k_front<<<FRONT_GATE + FRONT_CONV, 256, 0, stream>>>(x, gw, w1, sw1, w3, sw3, w2, sw2,
                                                         W13, W2B, XB, TOPE, TOPS);
    k_route<<<1, 256, 0, stream>>>(TOPE, TOPS, META, SLOT, RTOK, RSC);

    k_gemm1<<<dim3(NRT, 8, 1), 256, 0, stream>>>(XB, W13, META, RTOK, RSC, G);
    k_gemm2<<<dim3(NRT, 8, 1), 256, 0, stream>>>(G, W2B, META, Y);

    k_combine<<<(T_TOK * DIM / 8) / 256, 256, 0, stream>>>(Y, SLOT, out);
}

// Round 16
// 122.950 us; speedup vs baseline: 1.1076x; 1.1076x over previous
//
#include <hip/hip_runtime.h>

#define DIM 1024
#define HID 512
#define NE 8
#define T_TOK 4096
#define BMPAD 128
#define PAD_ROUTED (T_TOK*2 + NE*BMPAD)     // 9216
#define SHARED_BASE PAD_ROUTED              // 9216
#define TOTAL_SLOTS (SHARED_BASE + T_TOK)   // 13312
#define NRT 104                             // max row-tiles: <=72 routed + 32 shared

// meta layout: [26] routed_end, [32..] rt table (e,base)*NRT
#define M_REND 26
#define M_RT 32

// k_front block split
#define FRONT_GATE 256
#define FRONT_CONV 2048
// gemm1 grid: 832 gemm blocks + 128 w2-conv blocks
#define G1_BLOCKS 832
#define W2CONV_BLOCKS 128

typedef __attribute__((ext_vector_type(4))) float f32x4;
typedef __attribute__((ext_vector_type(8))) short s16x8;

__device__ __forceinline__ unsigned short f2bf(float f) {
    union { float f; unsigned int u; } v; v.f = f;
    unsigned int u = v.u;
    u += 0x7fffu + ((u >> 16) & 1u);   // RNE
    return (unsigned short)(u >> 16);
}
__device__ __forceinline__ float bf2f(unsigned short s) {
    union { unsigned int u; float f; } v; v.u = ((unsigned int)s) << 16;
    return v.f;
}

// async global(16B/lane) -> LDS (wave-uniform base + lane*16); global src may be per-lane
__device__ __forceinline__ void gload_lds16(const void* g, void* lds) {
    __builtin_amdgcn_global_load_lds(
        (const __attribute__((address_space(1))) unsigned int*)g,
        (__attribute__((address_space(3))) unsigned int*)lds, 16, 0, 0);
}

__device__ __forceinline__ unsigned long long pack4(f32x4 v) {
    unsigned long long o = 0;
    o |= (unsigned long long)f2bf(v[0]);
    o |= (unsigned long long)f2bf(v[1]) << 16;
    o |= (unsigned long long)f2bf(v[2]) << 32;
    o |= (unsigned long long)f2bf(v[3]) << 48;
    return o;
}

// ---------------- front: gate (blocks 0..255, no LDS) || conv w1/w3 + x (blocks 256..2303) ----------------
// wdst layout (contiguous): [w1(8E)][sw1][w3(8E)][sw3]   (w2 converted inside gemm1's grid)
__global__ __launch_bounds__(256) void k_front(const float* __restrict__ x,
                                               const float* __restrict__ gw,
                                               const float* __restrict__ w1,
                                               const float* __restrict__ sw1,
                                               const float* __restrict__ w3,
                                               const float* __restrict__ sw3,
                                               unsigned short* __restrict__ wdst,
                                               unsigned short* __restrict__ xb,
                                               int* __restrict__ top_e,
                                               float* __restrict__ top_s) {
    int bid = blockIdx.x, tid = threadIdx.x;
    if (bid >= FRONT_GATE) {
        // ---- streaming conversion: w1|sw1|w3|sw3 then x ----
        const long E0 = (long)NE * HID * DIM;   // 4194304
        const long S0 = E0;
        const long S1 = S0 + HID * DIM;
        const long S2 = S1 + E0;
        const long S3 = S2 + HID * DIM;         // 9437184
        const long TOT = S3 + (long)T_TOK * DIM; // 13631488
        long stride = (long)FRONT_CONV * 256 * 4;
        for (long i = ((long)(bid - FRONT_GATE) * 256 + tid) * 4; i < TOT; i += stride) {
            const float* src; unsigned short* dst; long off;
            if (i < S3) {
                dst = wdst + i;
                if      (i < S0) { src = w1;  off = i; }
                else if (i < S1) { src = sw1; off = i - S0; }
                else if (i < S2) { src = w3;  off = i - S1; }
                else             { src = sw3; off = i - S2; }
            } else { src = x; off = i - S3; dst = xb + off; }
            *(unsigned long long*)dst = pack4(*(const f32x4*)&src[off]);
        }
        return;
    }
    // ---- gate: 16 tokens per block, gw in registers (no LDS) ----
    int wv = tid >> 6, lane = tid & 63;
    f32x4 gwr[4][NE];
#pragma unroll
    for (int j0 = 0; j0 < 4; j0++) {
        int j = j0 * 64 + lane;
#pragma unroll
        for (int e = 0; e < NE; e++)
            gwr[j0][e] = *(const f32x4*)&gw[e * DIM + j * 4];
    }
    int t0 = bid * 16 + wv * 4;
    for (int tt = 0; tt < 4; tt++) {
        int t = t0 + tt;
        float p[NE];
#pragma unroll
        for (int e = 0; e < NE; e++) p[e] = 0.f;
        const f32x4* xr = (const f32x4*)(x + (size_t)t * DIM);
#pragma unroll
        for (int j0 = 0; j0 < 4; j0++) {
            f32x4 xv = xr[j0 * 64 + lane];
#pragma unroll
            for (int e = 0; e < NE; e++) {
                f32x4 wv4 = gwr[j0][e];
                p[e] += xv[0] * wv4[0] + xv[1] * wv4[1] + xv[2] * wv4[2] + xv[3] * wv4[3];
            }
        }
#pragma unroll
        for (int e = 0; e < NE; e++) {
            float v = p[e];
            for (int off = 32; off; off >>= 1) v += __shfl_xor(v, off, 64);
            p[e] = v;
        }
        if (lane == 0) {
            float s[NE];
#pragma unroll
            for (int e = 0; e < NE; e++) s[e] = 1.f / (1.f + expf(-p[e]));
            int e0 = 0;
#pragma unroll
            for (int e = 1; e < NE; e++) if (s[e] > s[e0]) e0 = e;
            int e1 = (e0 == 0) ? 1 : 0;
#pragma unroll
            for (int e = 0; e < NE; e++) if (e != e0 && s[e] > s[e1]) e1 = e;
            top_e[t * 2 + 0] = e0;  top_e[t * 2 + 1] = e1;
            top_s[t * 2 + 0] = s[e0]; top_s[t * 2 + 1] = s[e1];
        }
    }
}

// ---------------- route: single-block counting sort, wave-parallel scan ----------------
__global__ __launch_bounds__(256) void k_route(const int* __restrict__ top_e,
                                               const float* __restrict__ top_s,
                                               int* __restrict__ meta,
                                               int* __restrict__ slot_of,
                                               int* __restrict__ row_tok,
                                               float* __restrict__ row_sc) {
    __shared__ int lcnt[256][9];         // padded stride 9: no bank conflicts in scan
    __shared__ int cntS[NE], poffS[NE], padS[NE];
    int tid = threadIdx.x;
    int base = tid * 32;                 // 256 threads x 32 pairs = 8192

    int c0=0,c1=0,c2=0,c3=0,c4=0,c5=0,c6=0,c7=0;
    for (int i = 0; i < 32; i++) {
        int e = top_e[base + i];
        c0 += (e==0); c1 += (e==1); c2 += (e==2); c3 += (e==3);
        c4 += (e==4); c5 += (e==5); c6 += (e==6); c7 += (e==7);
    }
    lcnt[tid][0]=c0; lcnt[tid][1]=c1; lcnt[tid][2]=c2; lcnt[tid][3]=c3;
    lcnt[tid][4]=c4; lcnt[tid][5]=c5; lcnt[tid][6]=c6; lcnt[tid][7]=c7;
    __syncthreads();
    // parallel exclusive scan per expert: 8 groups of 32 lanes
    {
        int e = tid >> 5, l = tid & 31;
        int tmp[8], s = 0;
#pragma unroll
        for (int k = 0; k < 8; k++) { tmp[k] = lcnt[l * 8 + k][e]; s += tmp[k]; }
        int inc = s;
#pragma unroll
        for (int off = 1; off < 32; off <<= 1) {
            int v = __shfl_up(inc, off, 32);
            if (l >= off) inc += v;
        }
        int run = inc - s;               // exclusive prefix
        if (l == 31) cntS[e] = inc;
#pragma unroll
        for (int k = 0; k < 8; k++) { lcnt[l * 8 + k][e] = run; run += tmp[k]; }
    }
    __syncthreads();
    if (tid == 0) {
        int off = 0, rt = 0;
        for (int e = 0; e < NE; e++) {
            poffS[e] = off;
            int pad = ((cntS[e] + BMPAD - 1) / BMPAD) * BMPAD;
            padS[e] = pad;
            for (int b = 0; b * BMPAD < pad; b++) {
                meta[M_RT + rt * 2] = e;
                meta[M_RT + rt * 2 + 1] = off + b * BMPAD;
                rt++;
            }
            off += pad;
        }
        meta[M_REND] = off;
        for (int b = 0; b < T_TOK / BMPAD; b++) {          // 32 shared tiles (e=8)
            meta[M_RT + rt * 2] = NE;
            meta[M_RT + rt * 2 + 1] = SHARED_BASE + b * BMPAD;
            rt++;
        }
        for (; rt < NRT; rt++) { meta[M_RT + rt * 2] = -1; meta[M_RT + rt * 2 + 1] = 0; }
    }
    __syncthreads();
    int p0 = poffS[0] + lcnt[tid][0], p1 = poffS[1] + lcnt[tid][1];
    int p2 = poffS[2] + lcnt[tid][2], p3 = poffS[3] + lcnt[tid][3];
    int p4 = poffS[4] + lcnt[tid][4], p5 = poffS[5] + lcnt[tid][5];
    int p6 = poffS[6] + lcnt[tid][6], p7 = poffS[7] + lcnt[tid][7];
    for (int i = 0; i < 32; i++) {
        int p = base + i;
        int e = top_e[p];
        int slot = 0;
        slot = (e==0) ? p0 : slot;  p0 += (e==0);
        slot = (e==1) ? p1 : slot;  p1 += (e==1);
        slot = (e==2) ? p2 : slot;  p2 += (e==2);
        slot = (e==3) ? p3 : slot;  p3 += (e==3);
        slot = (e==4) ? p4 : slot;  p4 += (e==4);
        slot = (e==5) ? p5 : slot;  p5 += (e==5);
        slot = (e==6) ? p6 : slot;  p6 += (e==6);
        slot = (e==7) ? p7 : slot;  p7 += (e==7);
        slot_of[p] = slot;
        row_tok[slot] = p >> 1;
        row_sc[slot] = top_s[p];
    }
    __syncthreads();
    // fill pad rows (score 0 -> zero contribution)
    for (int e = 0; e < NE; e++) {
        int s0 = poffS[e] + cntS[e], s1 = poffS[e] + padS[e];
        for (int i = s0 + tid; i < s1; i += 256) { row_tok[i] = 0; row_sc[i] = 0.f; }
    }
}

// ---------------- GEMM1 (blocks 0..831) || w2 conv (blocks 832..959) ----------------
// gemm1: 128x64 tile, BK=64, 512 threads (8 waves), fused gather + SwiGLU.
// wave (wr 0..1, wc 0..3) owns 64 rows x 16 cols of g (for both w1 and w3 paths)
__global__ __launch_bounds__(512) void k_gemm1(const unsigned short* __restrict__ xb,
                                               const unsigned short* __restrict__ w1b,
                                               const unsigned short* __restrict__ w3b,
                                               const int* __restrict__ meta,
                                               const int* __restrict__ row_tok,
                                               const float* __restrict__ row_sc,
                                               unsigned short* __restrict__ g,
                                               const float* __restrict__ w2,
                                               const float* __restrict__ sw2,
                                               unsigned short* __restrict__ w2b) {
    int flat = blockIdx.x, tid = threadIdx.x;
    if (flat >= G1_BLOCKS) {
        // ---- w2|sw2 -> bf16 grid-stride (runs concurrently with gemm1 blocks;
        //      stream order guarantees completion before k_gemm2 launch) ----
        const long NW2 = (long)NE * DIM * HID;      // 8388608
        const long TOTC = NW2 + (long)DIM * HID;    // 9437184
        long stride = (long)W2CONV_BLOCKS * 512 * 4;
        for (long i = ((long)(flat - G1_BLOCKS) * 512 + tid) * 4; i < TOTC; i += stride) {
            const float* src = (i < NW2) ? w2 : sw2;
            long off = (i < NW2) ? i : i - NW2;
            *(unsigned long long*)&w2b[i] = pack4(*(const f32x4*)&src[off]);
        }
        return;
    }
    int work = (flat & 7) * NRT + (flat >> 3);       // bijective XCD chunking (832 = 8*104)
    int rt = work >> 3, ct = work & 7;
    int e = meta[M_RT + rt * 2];
    if (e < 0) return;
    int rowbase = meta[M_RT + rt * 2 + 1];
    int nbase = ct * 64;
    bool shared_tile = (e == NE);

    __shared__ __align__(16) unsigned short As[2][128 * 64];
    __shared__ __align__(16) unsigned short B1s[2][64 * 64];
    __shared__ __align__(16) unsigned short B3s[2][64 * 64];

    int w = tid >> 6, lane = tid & 63;
    int l15 = lane & 15, kq = lane >> 4;
    int wr = w >> 2, wc = w & 3;
    int lr = lane >> 3;
    int lcs = ((lane & 7) ^ lr) << 4;   // XOR-swizzled source byte col (write side of T2)
    int rx = l15 & 7;                   // read-side XOR key

    // per-lane A sources: 2 issues x (8 waves x 8 rows), constant across K
    const char* asrc[2];
#pragma unroll
    for (int j = 0; j < 2; j++) {
        int slot = rowbase + j * 64 + w * 8 + lr;
        int tok = shared_tile ? (slot - SHARED_BASE) : row_tok[slot];
        asrc[j] = (const char*)xb + (size_t)tok * (DIM * 2) + lcs;
    }
    const char* B1b = (const char*)(w1b + (size_t)e * HID * DIM + (size_t)nbase * DIM);
    const char* B3b = (const char*)(w3b + (size_t)e * HID * DIM + (size_t)nbase * DIM);

    f32x4 acc1[4], acc3[4];
#pragma unroll
    for (int m = 0; m < 4; m++) {
        acc1[m] = (f32x4){0.f, 0.f, 0.f, 0.f};
        acc3[m] = (f32x4){0.f, 0.f, 0.f, 0.f};
    }

    auto STAGE = [&](int b, int k0) {                 // 4 issues per wave
#pragma unroll
        for (int j = 0; j < 2; j++) {
            int r0 = j * 64 + w * 8;
            gload_lds16(asrc[j] + k0 * 2, (char*)As[b] + r0 * 128);
        }
        int r0 = w * 8;
        gload_lds16(B1b + (size_t)(r0 + lr) * (DIM * 2) + k0 * 2 + lcs,
                    (char*)B1s[b] + r0 * 128);
        gload_lds16(B3b + (size_t)(r0 + lr) * (DIM * 2) + k0 * 2 + lcs,
                    (char*)B3s[b] + r0 * 128);
    };

    STAGE(0, 0);
#pragma unroll 1
    for (int t = 0; t < 16; t++) {
        int cur = t & 1;
        if (t < 15) {
            STAGE(cur ^ 1, (t + 1) * 64);
            asm volatile("s_waitcnt vmcnt(4)" ::: "memory");  // stage(t) done, stage(t+1) in flight
        } else {
            asm volatile("s_waitcnt vmcnt(0)" ::: "memory");
        }
        __builtin_amdgcn_sched_barrier(0);
        __builtin_amdgcn_s_barrier();
        __builtin_amdgcn_sched_barrier(0);
#pragma unroll
        for (int kk = 0; kk < 64; kk += 32) {
            int sl = kq + (kk >> 3);    // 16B slot 0..7
            s16x8 af[4], b1f, b3f;
#pragma unroll
            for (int m = 0; m < 4; m++)
                af[m] = *(const s16x8*)&As[cur][(wr * 64 + m * 16 + l15) * 64 + ((sl ^ rx) << 3)];
            b1f = *(const s16x8*)&B1s[cur][(wc * 16 + l15) * 64 + ((sl ^ rx) << 3)];
            b3f = *(const s16x8*)&B3s[cur][(wc * 16 + l15) * 64 + ((sl ^ rx) << 3)];
#pragma unroll
            for (int m = 0; m < 4; m++) {
                acc1[m] = __builtin_amdgcn_mfma_f32_16x16x32_bf16(af[m], b1f, acc1[m], 0, 0, 0);
                acc3[m] = __builtin_amdgcn_mfma_f32_16x16x32_bf16(af[m], b3f, acc3[m], 0, 0, 0);
            }
        }
        __builtin_amdgcn_sched_barrier(0);
        __builtin_amdgcn_s_barrier();
    }
#pragma unroll
    for (int m = 0; m < 4; m++)
#pragma unroll
        for (int i = 0; i < 4; i++) {
            int row = rowbase + wr * 64 + m * 16 + kq * 4 + i;
            float sc = shared_tile ? 1.f : row_sc[row];
            float h1 = sc * acc1[m][i], h3 = sc * acc3[m][i];
            float gv = h1 / (1.f + expf(-h1)) * h3;
            int col = nbase + wc * 16 + l15;
            g[(size_t)row * HID + col] = f2bf(gv);
        }
}

// ---------------- GEMM2: 128x128 tile, BK=64, 512 threads (8 waves), y = g W2^T ----------------
__global__ __launch_bounds__(512) void k_gemm2(const unsigned short* __restrict__ g,
                                               const unsigned short* __restrict__ w2b,
                                               const int* __restrict__ meta,
                                               unsigned short* __restrict__ y) {
    int flat = blockIdx.y * NRT + blockIdx.x;
    int work = (flat & 7) * NRT + (flat >> 3);
    int rt = work >> 3, ct = work & 7;
    int e = meta[M_RT + rt * 2];
    if (e < 0) return;
    int rowbase = meta[M_RT + rt * 2 + 1];
    int nbase = ct * 128;

    __shared__ __align__(16) unsigned short As[2][128 * 64];
    __shared__ __align__(16) unsigned short Bs[2][128 * 64];

    int tid = threadIdx.x, w = tid >> 6, lane = tid & 63;
    int l15 = lane & 15, kq = lane >> 4;
    int wr = w >> 2, wc = w & 3;
    int lr = lane >> 3;
    int lcs = ((lane & 7) ^ lr) << 4;
    int rx = l15 & 7;

    const char* Ab = (const char*)(g + (size_t)rowbase * HID);
    const char* Bb = (const char*)(w2b + (size_t)e * DIM * HID + (size_t)nbase * HID);

    f32x4 acc[4][2];
#pragma unroll
    for (int m = 0; m < 4; m++)
#pragma unroll
        for (int n = 0; n < 2; n++) acc[m][n] = (f32x4){0.f, 0.f, 0.f, 0.f};

    auto STAGE = [&](int b, int k0) {                 // 4 issues per wave
#pragma unroll
        for (int j = 0; j < 2; j++) {
            int r0 = j * 64 + w * 8;
            gload_lds16(Ab + (size_t)(r0 + lr) * (HID * 2) + k0 * 2 + lcs,
                        (char*)As[b] + r0 * 128);
            gload_lds16(Bb + (size_t)(r0 + lr) * (HID * 2) + k0 * 2 + lcs,
                        (char*)Bs[b] + r0 * 128);
        }
    };

    STAGE(0, 0);
#pragma unroll 1
    for (int t = 0; t < 8; t++) {
        int cur = t & 1;
        if (t < 7) {
            STAGE(cur ^ 1, (t + 1) * 64);
            asm volatile("s_waitcnt vmcnt(4)" ::: "memory");
        } else {
            asm volatile("s_waitcnt vmcnt(0)" ::: "memory");
        }
        __builtin_amdgcn_sched_barrier(0);
        __builtin_amdgcn_s_barrier();
        __builtin_amdgcn_sched_barrier(0);
#pragma unroll
        for (int kk = 0; kk < 64; kk += 32) {
            int sl = kq + (kk >> 3);
            s16x8 af[4], bf[2];
#pragma unroll
            for (int m = 0; m < 4; m++)
                af[m] = *(const s16x8*)&As[cur][(wr * 64 + m * 16 + l15) * 64 + ((sl ^ rx) << 3)];
#pragma unroll
            for (int n = 0; n < 2; n++)
                bf[n] = *(const s16x8*)&Bs[cur][(wc * 32 + n * 16 + l15) * 64 + ((sl ^ rx) << 3)];
#pragma unroll
            for (int m = 0; m < 4; m++)
#pragma unroll
                for (int n = 0; n < 2; n++)
                    acc[m][n] = __builtin_amdgcn_mfma_f32_16x16x32_bf16(af[m], bf[n], acc[m][n], 0, 0, 0);
        }
        __builtin_amdgcn_sched_barrier(0);
        __builtin_amdgcn_s_barrier();
    }
#pragma unroll
    for (int m = 0; m < 4; m++)
#pragma unroll
        for (int n = 0; n < 2; n++)
#pragma unroll
            for (int i = 0; i < 4; i++) {
                int row = rowbase + wr * 64 + m * 16 + kq * 4 + i;
                int col = nbase + wc * 32 + n * 16 + l15;
                y[(size_t)row * DIM + col] = f2bf(acc[m][n][i]);
            }
}

// ---------------- combine: out[t] = y[s0]+y[s1]+y[shared+t] (fp32 out) ----------------
__global__ __launch_bounds__(256) void k_combine(const unsigned short* __restrict__ y,
                                                 const int* __restrict__ slot_of,
                                                 float* __restrict__ out) {
    int idx = blockIdx.x * 256 + threadIdx.x;   // T_TOK*DIM/8 total
    int t = idx >> 7;
    int d = (idx & 127) << 3;
    int s0 = slot_of[2 * t], s1 = slot_of[2 * t + 1];
    s16x8 a = *(const s16x8*)&y[(size_t)s0 * DIM + d];
    s16x8 b = *(const s16x8*)&y[(size_t)s1 * DIM + d];
    s16x8 c = *(const s16x8*)&y[(size_t)(SHARED_BASE + t) * DIM + d];
    f32x4 o0, o1;
#pragma unroll
    for (int i = 0; i < 4; i++) {
        o0[i] = bf2f((unsigned short)a[i]) + bf2f((unsigned short)b[i]) + bf2f((unsigned short)c[i]);
        o1[i] = bf2f((unsigned short)a[i + 4]) + bf2f((unsigned short)b[i + 4]) + bf2f((unsigned short)c[i + 4]);
    }
    *(f32x4*)&out[(size_t)t * DIM + d + 0] = o0;
    *(f32x4*)&out[(size_t)t * DIM + d + 4] = o1;
}

extern "C" void kernel_launch(void* const* d_in, const int* in_sizes, int n_in,
                              void* d_out, int out_size, void* d_ws, size_t ws_size,
                              hipStream_t stream) {
    const float* x   = (const float*)d_in[0];
    const float* gw  = (const float*)d_in[1];
    const float* w1  = (const float*)d_in[2];
    const float* w2  = (const float*)d_in[3];
    const float* w3  = (const float*)d_in[4];
    const float* sw1 = (const float*)d_in[5];
    const float* sw2 = (const float*)d_in[6];
    const float* sw3 = (const float*)d_in[7];
    float* out = (float*)d_out;

    char* ws = (char*)d_ws;
    size_t off = 0;
    // contiguous bf16 weight block: [w1|sw1][w3|sw3][w2|sw2]
    unsigned short* W1B = (unsigned short*)(ws + off); off += (size_t)9 * HID * DIM * 2;
    unsigned short* W3B = (unsigned short*)(ws + off); off += (size_t)9 * HID * DIM * 2;
    unsigned short* W2B = (unsigned short*)(ws + off); off += (size_t)9 * DIM * HID * 2;
    unsigned short* A1  = (unsigned short*)(ws + off); off += (size_t)TOTAL_SLOTS * DIM * 2; // Y aliases
    unsigned short* G   = (unsigned short*)(ws + off); off += (size_t)TOTAL_SLOTS * HID * 2;
    unsigned short* Y   = A1;                                // Y written by gemm2
    unsigned short* XB  = A1 + (size_t)SHARED_BASE * DIM;    // bf16(x): xb IS Y's shared region
    int*   TOPE = (int*)(ws + off);   off += T_TOK * 2 * 4;
    float* TOPS = (float*)(ws + off); off += T_TOK * 2 * 4;
    int*   SLOT = (int*)(ws + off);   off += T_TOK * 2 * 4;
    int*   RTOK = (int*)(ws + off);   off += TOTAL_SLOTS * 4;
    float* RSC  = (float*)(ws + off); off += TOTAL_SLOTS * 4;
    int*   META = (int*)(ws + off);   off += 1024;

    // fused front: gate || w1/w3 + x -> bf16 (w2 conv deferred into gemm1's grid)
    k_front<<<FRONT_GATE + FRONT_CONV, 256, 0, stream>>>(x, gw, w1, sw1, w3, sw3,
                                                         W1B, XB, TOPE, TOPS);
    k_route<<<1, 256, 0, stream>>>(TOPE, TOPS, META, SLOT, RTOK, RSC);

    // gemm1 (832 blocks) || w2 conversion (128 blocks) — conv done before gemm2 by stream order
    k_gemm1<<<G1_BLOCKS + W2CONV_BLOCKS, 512, 0, stream>>>(XB, W1B, W3B, META, RTOK, RSC, G,
                                                           w2, sw2, W2B);
    k_gemm2<<<dim3(NRT, 8, 1), 512, 0, stream>>>(G, W2B, META, Y);

    k_combine<<<(T_TOK * DIM / 8) / 256, 256, 0, stream>>>(Y, SLOT, out);
}